// Round 11
// baseline (58.231 us; speedup 1.0000x reference)
//
#include <hip/hip_runtime.h>
#include <math.h>

#define H 8
#define B 64
#define D 512
#define NB 256                            // value buckets
#define EPS 1e-8f
#define INV_SQRT_D 0.04419417382415922f   // 1/sqrt(512)
#define LN2 0.6931471805599453f
#define EPS_LN2 6.931471805599453e-9f     // EPS * ln(2)
#define CUTOFF 34.0f                      // drop weights below 2^-34
#define TMAX_FALLBACK 36.0f               // flat softmax -> full window (exact)

__device__ __forceinline__ float fast_rcp(float x) { return __builtin_amdgcn_rcpf(x); }
__device__ __forceinline__ float fast_exp2(float x) { return __builtin_amdgcn_exp2f(x); }

__device__ __forceinline__ int bucketof(float xx, float vmin, float inv_w) {
    float f = (xx - vmin) * inv_w;
    f = fminf(f, (float)(NB - 1));
    int bb = (int)f;
    return bb < 0 ? 0 : bb;
}

// ---------------------------------------------------------------------------
// One block per (h,b), 512 threads.
//  1. compute q,k,v for own column t
//  2. block min/max of q -> 256-bucket counting sort of (q,v) by value
//     (hist + wave0 prefix scan + atomic scatter; ~10 instr/elem, no bitonic)
//  3. pass 1: brute dmin over sorted q (2 VALU/elem, exact for any data)
//  4. pass 2: window = contiguous range [pf[bkt(k-rad)], pf[bkt(k+rad)+1])
//     -- superset of the true window; every scanned term computed fully.
//     Flat-softmax rows: rad=INF -> full range (exact brute fallback).
//  5. write att row (coalesced, original row order)
// Skipped terms are < 2^-34 relative to l >= 1: below fp32 resolution.
// ---------------------------------------------------------------------------
__global__ __launch_bounds__(512) void attn_bucket(
    const float* __restrict__ x,
    const float* __restrict__ Wq, const float* __restrict__ bq,
    const float* __restrict__ Wk, const float* __restrict__ bk,
    const float* __restrict__ Wv, const float* __restrict__ bv,
    float* __restrict__ ws_att)
{
    const int hb = blockIdx.x;          // 0..H*B-1
    const int h = hb >> 6;              // B == 64
    const int b = hb & 63;
    const int t = threadIdx.x;

    __shared__ __align__(16) float sq[D];
    __shared__ __align__(16) float sv[D];
    __shared__ int pf[NB + 1];
    __shared__ int cnt[NB];
    __shared__ float redlo[8], redhi[8];

    const float xv = x[b * D + t];
    const float q = fmaf(Wq[h * D + t], xv, bq[h * D + t]);
    const float v = fmaf(Wv[h * D + t], xv, bv[h * D + t]);
    const float k = fmaf(Wk[h * D + t], xv, bk[h * D + t]);

    // --- block min/max of q ---
    float wlo = q, whi = q;
    #pragma unroll
    for (int off = 1; off < 64; off <<= 1) {
        wlo = fminf(wlo, __shfl_xor(wlo, off, 64));
        whi = fmaxf(whi, __shfl_xor(whi, off, 64));
    }
    if ((t & 63) == 0) { redlo[t >> 6] = wlo; redhi[t >> 6] = whi; }
    if (t < NB) cnt[t] = 0;
    __syncthreads();
    float vmin = redlo[0], vmax = redhi[0];
    #pragma unroll
    for (int i = 1; i < 8; ++i) {
        vmin = fminf(vmin, redlo[i]);
        vmax = fmaxf(vmax, redhi[i]);
    }
    const float range = vmax - vmin;
    const float inv_w = (range > 1e-30f) ? ((float)NB / range) : 0.f;

    // --- histogram ---
    const int myb = bucketof(q, vmin, inv_w);
    atomicAdd(&cnt[myb], 1);
    __syncthreads();

    // --- exclusive prefix scan (wave 0: 4 bins/lane) ---
    if (t < 64) {
        const int c0 = cnt[4 * t + 0], c1 = cnt[4 * t + 1];
        const int c2 = cnt[4 * t + 2], c3 = cnt[4 * t + 3];
        const int s = c0 + c1 + c2 + c3;
        int sc = s;
        #pragma unroll
        for (int off = 1; off < 64; off <<= 1) {
            const int n = __shfl_up(sc, off, 64);
            if ((t & 63) >= off) sc += n;
        }
        const int excl = sc - s;
        pf[4 * t + 0] = excl;
        pf[4 * t + 1] = excl + c0;
        pf[4 * t + 2] = excl + c0 + c1;
        pf[4 * t + 3] = excl + c0 + c1 + c2;
        if (t == 63) pf[NB] = sc;           // == 512
        cnt[4 * t + 0] = 0; cnt[4 * t + 1] = 0;
        cnt[4 * t + 2] = 0; cnt[4 * t + 3] = 0;
    }
    __syncthreads();

    // --- scatter (bucket-ordered; within-bucket order via LDS atomic) ---
    const int pos = pf[myb] + atomicAdd(&cnt[myb], 1);
    sq[pos] = q; sv[pos] = v;
    __syncthreads();

    // --- pass 1: brute dmin over sorted q (values identical, just permuted) ---
    const float4* q4 = reinterpret_cast<const float4*>(sq);
    float m0 = INFINITY, m1 = INFINITY, m2 = INFINITY, m3 = INFINITY;
    for (int j = 0; j < D / 4; ++j) {
        const float4 qq = q4[j];
        m0 = fminf(m0, fabsf(qq.x - k));
        m1 = fminf(m1, fabsf(qq.y - k));
        m2 = fminf(m2, fabsf(qq.z - k));
        m3 = fminf(m3, fabsf(qq.w - k));
    }
    const float dmin = fminf(fminf(m0, m1), fminf(m2, m3));
    const float tmax = fast_rcp(fmaf(dmin, LN2, EPS_LN2));

    // --- window bounds from bucket prefix table ---
    int lo_i, hi_i;
    if (tmax < TMAX_FALLBACK) {
        lo_i = 0; hi_i = D;                 // flat softmax: exact full scan
    } else {
        const float rad = fast_rcp((tmax - CUTOFF) * LN2) * 1.001f;
        const int blo = bucketof(k - rad, vmin, inv_w);
        const int bhi = bucketof(k + rad, vmin, inv_w);
        lo_i = pf[blo];
        hi_i = pf[bhi + 1];
    }

    // --- pass 2: full-precision accumulation over the window superset ---
    float l = 0.f, a = 0.f;
    for (int s = lo_i; s < hi_i; ++s) {
        const float d = fabsf(sq[s] - k);
        const float e = fast_exp2(fast_rcp(fmaf(d, LN2, EPS_LN2)) - tmax);
        l += e; a = fmaf(e, sv[s], a);
    }

    ws_att[hb * D + t] = a * fast_rcp(l) * INV_SQRT_D;
}

// out[b,i] = x[b,i] + sum_h att[h,b,i]  (deterministic h-sum)
__global__ __launch_bounds__(256) void reduce_h(
    const float* __restrict__ x, const float* __restrict__ att,
    float* __restrict__ out)
{
    const int i = blockIdx.x * 256 + threadIdx.x;   // 0..B*D-1
    float s = x[i];
    #pragma unroll
    for (int h = 0; h < H; ++h) s += att[h * (B * D) + i];
    out[i] = s;
}

// ---------------------------------------------------------------------------
// Fallback (ws too small): fully fused exact kernel.
// ---------------------------------------------------------------------------
__global__ __launch_bounds__(512) void attn_fused(
    const float* __restrict__ x,
    const float* __restrict__ Wq, const float* __restrict__ bq,
    const float* __restrict__ Wk, const float* __restrict__ bk,
    const float* __restrict__ Wv, const float* __restrict__ bv,
    float* __restrict__ out)
{
    const int b = blockIdx.x;
    const int t = threadIdx.x;

    __shared__ float qs[D];
    __shared__ float vs[D];

    const float xv = x[b * D + t];
    float total = 0.f;

    for (int h = 0; h < H; ++h) {
        __syncthreads();
        qs[t] = Wq[h * D + t] * xv + bq[h * D + t];
        vs[t] = Wv[h * D + t] * xv + bv[h * D + t];
        const float ki = Wk[h * D + t] * xv + bk[h * D + t];
        __syncthreads();

        const float4* q4 = reinterpret_cast<const float4*>(qs);
        const float4* v4 = reinterpret_cast<const float4*>(vs);

        float d0 = INFINITY, d1 = INFINITY, d2 = INFINITY, d3 = INFINITY;
        for (int j = 0; j < D / 4; ++j) {
            float4 qq = q4[j];
            d0 = fminf(d0, fabsf(qq.x - ki));
            d1 = fminf(d1, fabsf(qq.y - ki));
            d2 = fminf(d2, fabsf(qq.z - ki));
            d3 = fminf(d3, fabsf(qq.w - ki));
        }
        const float dmin = fminf(fminf(d0, d1), fminf(d2, d3));
        const float tmax = fast_rcp(fmaf(dmin, LN2, EPS_LN2));

        float l0 = 0.f, l1 = 0.f, l2 = 0.f, l3 = 0.f;
        float a0 = 0.f, a1 = 0.f, a2 = 0.f, a3 = 0.f;
        for (int j = 0; j < D / 4; ++j) {
            float4 qq = q4[j];
            float4 vv = v4[j];
            float e0 = fast_exp2(fast_rcp(fmaf(fabsf(qq.x - ki), LN2, EPS_LN2)) - tmax);
            float e1 = fast_exp2(fast_rcp(fmaf(fabsf(qq.y - ki), LN2, EPS_LN2)) - tmax);
            float e2 = fast_exp2(fast_rcp(fmaf(fabsf(qq.z - ki), LN2, EPS_LN2)) - tmax);
            float e3 = fast_exp2(fast_rcp(fmaf(fabsf(qq.w - ki), LN2, EPS_LN2)) - tmax);
            l0 += e0; a0 = fmaf(e0, vv.x, a0);
            l1 += e1; a1 = fmaf(e1, vv.y, a1);
            l2 += e2; a2 = fmaf(e2, vv.z, a2);
            l3 += e3; a3 = fmaf(e3, vv.w, a3);
        }
        const float l = (l0 + l1) + (l2 + l3);
        const float a = (a0 + a1) + (a2 + a3);
        total += a * fast_rcp(l) * INV_SQRT_D;
    }
    out[b * D + t] = xv + total;
}

extern "C" void kernel_launch(void* const* d_in, const int* in_sizes, int n_in,
                              void* d_out, int out_size, void* d_ws, size_t ws_size,
                              hipStream_t stream) {
    const float* x  = (const float*)d_in[0];
    const float* Wq = (const float*)d_in[1];
    const float* bq = (const float*)d_in[2];
    const float* Wk = (const float*)d_in[3];
    const float* bk = (const float*)d_in[4];
    const float* Wv = (const float*)d_in[5];
    const float* bv = (const float*)d_in[6];
    float* out = (float*)d_out;

    const size_t need = (size_t)H * B * D * sizeof(float);   // 1 MB

    if (ws_size >= need) {
        float* ws = (float*)d_ws;
        attn_bucket<<<H * B, 512, 0, stream>>>(x, Wq, bq, Wk, bk, Wv, bv, ws);
        reduce_h<<<(B * D) / 256, 256, 0, stream>>>(x, ws, out);
    } else {
        attn_fused<<<B, 512, 0, stream>>>(x, Wq, bq, Wk, bk, Wv, bv, out);
    }
}

// Round 12
// 38.808 us; speedup vs baseline: 1.5005x; 1.5005x over previous
//
#include <hip/hip_runtime.h>
#include <math.h>

#define H 8
#define B 64
#define D 512
#define EPS 1e-8f
#define INV_SQRT_D 0.04419417382415922f   // 1/sqrt(512)
#define LN2 0.6931471805599453f
#define EPS_LN2 6.931471805599453e-9f     // EPS * ln(2)

__device__ __forceinline__ float fast_rcp(float x) { return __builtin_amdgcn_rcpf(x); }
__device__ __forceinline__ float fast_exp2(float x) { return __builtin_amdgcn_exp2f(x); }

// ---------------------------------------------------------------------------
// One block per (h,b), 1024 threads = (row r, j-half). Brute-force two-pass
// softmax per half (proven issue-bound structure), in-LDS merge of halves.
// 2 blocks/CU -> 32 waves/CU (full occupancy). No merge kernel, no ws
// round-trip for partials.
// ---------------------------------------------------------------------------
__global__ __launch_bounds__(1024, 2) void attn_half(
    const float* __restrict__ x,
    const float* __restrict__ Wq, const float* __restrict__ bq,
    const float* __restrict__ Wk, const float* __restrict__ bk,
    const float* __restrict__ Wv, const float* __restrict__ bv,
    float* __restrict__ ws_att)
{
    const int hb = blockIdx.x;          // 0..H*B-1
    const int h = hb >> 6;              // B == 64
    const int b = hb & 63;
    const int t = threadIdx.x;          // 0..1023
    const int r = t & (D - 1);          // row 0..511
    const int half = t >> 9;            // j-half 0/1

    __shared__ __align__(16) float qs[D];
    __shared__ __align__(16) float vs[D];
    __shared__ float pT[D], pL[D], pA[D];   // half-1 partials

    const float xv = x[b * D + r];
    const float k = fmaf(Wk[h * D + r], xv, bk[h * D + r]);
    if (half == 0) {
        qs[r] = fmaf(Wq[h * D + r], xv, bq[h * D + r]);
        vs[r] = fmaf(Wv[h * D + r], xv, bv[h * D + r]);
    }
    __syncthreads();

    const float4* q4 = reinterpret_cast<const float4*>(qs) + half * (D / 8);
    const float4* v4 = reinterpret_cast<const float4*>(vs) + half * (D / 8);

    // Pass 1: dmin over this half (sub + min-with-abs, 4 chains)
    float m0 = INFINITY, m1 = INFINITY, m2 = INFINITY, m3 = INFINITY;
    for (int j = 0; j < D / 8; ++j) {
        const float4 qq = q4[j];
        m0 = fminf(m0, fabsf(qq.x - k));
        m1 = fminf(m1, fabsf(qq.y - k));
        m2 = fminf(m2, fabsf(qq.z - k));
        m3 = fminf(m3, fabsf(qq.w - k));
    }
    const float dmin = fminf(fminf(m0, m1), fminf(m2, m3));
    const float tmax = fast_rcp(fmaf(dmin, LN2, EPS_LN2));

    // Pass 2: l, a relative to this half's tmax (4 independent chains)
    float l0 = 0.f, l1 = 0.f, l2 = 0.f, l3 = 0.f;
    float a0 = 0.f, a1 = 0.f, a2 = 0.f, a3 = 0.f;
    for (int j = 0; j < D / 8; ++j) {
        const float4 qq = q4[j];
        const float4 vv = v4[j];
        const float e0 = fast_exp2(fast_rcp(fmaf(fabsf(qq.x - k), LN2, EPS_LN2)) - tmax);
        const float e1 = fast_exp2(fast_rcp(fmaf(fabsf(qq.y - k), LN2, EPS_LN2)) - tmax);
        const float e2 = fast_exp2(fast_rcp(fmaf(fabsf(qq.z - k), LN2, EPS_LN2)) - tmax);
        const float e3 = fast_exp2(fast_rcp(fmaf(fabsf(qq.w - k), LN2, EPS_LN2)) - tmax);
        l0 += e0; a0 = fmaf(e0, vv.x, a0);
        l1 += e1; a1 = fmaf(e1, vv.y, a1);
        l2 += e2; a2 = fmaf(e2, vv.z, a2);
        l3 += e3; a3 = fmaf(e3, vv.w, a3);
    }
    const float l = (l0 + l1) + (l2 + l3);
    const float a = (a0 + a1) + (a2 + a3);

    // Publish half-1 partials, merge in half-0 threads
    if (half == 1) { pT[r] = tmax; pL[r] = l; pA[r] = a; }
    __syncthreads();
    if (half == 0) {
        const float T1 = pT[r], L1 = pL[r], A1 = pA[r];
        const float m  = fmaxf(tmax, T1);
        const float s0 = fast_exp2(tmax - m);
        const float s1 = fast_exp2(T1 - m);
        const float L  = fmaf(L1, s1, l * s0);
        const float A  = fmaf(A1, s1, a * s0);
        ws_att[hb * D + r] = A * fast_rcp(L) * INV_SQRT_D;
    }
}

// out[b,i] = x[b,i] + sum_h att[h,b,i]  (deterministic h-sum)
__global__ __launch_bounds__(256) void reduce_h(
    const float* __restrict__ x, const float* __restrict__ att,
    float* __restrict__ out)
{
    const int i = blockIdx.x * 256 + threadIdx.x;   // 0..B*D-1
    float s = x[i];
    #pragma unroll
    for (int h = 0; h < H; ++h) s += att[h * (B * D) + i];
    out[i] = s;
}

// ---------------------------------------------------------------------------
// Fallback (ws too small): fully fused exact kernel.
// ---------------------------------------------------------------------------
__global__ __launch_bounds__(512) void attn_fused(
    const float* __restrict__ x,
    const float* __restrict__ Wq, const float* __restrict__ bq,
    const float* __restrict__ Wk, const float* __restrict__ bk,
    const float* __restrict__ Wv, const float* __restrict__ bv,
    float* __restrict__ out)
{
    const int b = blockIdx.x;
    const int t = threadIdx.x;

    __shared__ float qs[D];
    __shared__ float vs[D];

    const float xv = x[b * D + t];
    float total = 0.f;

    for (int h = 0; h < H; ++h) {
        __syncthreads();
        qs[t] = Wq[h * D + t] * xv + bq[h * D + t];
        vs[t] = Wv[h * D + t] * xv + bv[h * D + t];
        const float ki = Wk[h * D + t] * xv + bk[h * D + t];
        __syncthreads();

        const float4* q4 = reinterpret_cast<const float4*>(qs);
        const float4* v4 = reinterpret_cast<const float4*>(vs);

        float d0 = INFINITY, d1 = INFINITY, d2 = INFINITY, d3 = INFINITY;
        for (int j = 0; j < D / 4; ++j) {
            float4 qq = q4[j];
            d0 = fminf(d0, fabsf(qq.x - ki));
            d1 = fminf(d1, fabsf(qq.y - ki));
            d2 = fminf(d2, fabsf(qq.z - ki));
            d3 = fminf(d3, fabsf(qq.w - ki));
        }
        const float dmin = fminf(fminf(d0, d1), fminf(d2, d3));
        const float tmax = fast_rcp(fmaf(dmin, LN2, EPS_LN2));

        float l0 = 0.f, l1 = 0.f, l2 = 0.f, l3 = 0.f;
        float a0 = 0.f, a1 = 0.f, a2 = 0.f, a3 = 0.f;
        for (int j = 0; j < D / 4; ++j) {
            float4 qq = q4[j];
            float4 vv = v4[j];
            float e0 = fast_exp2(fast_rcp(fmaf(fabsf(qq.x - ki), LN2, EPS_LN2)) - tmax);
            float e1 = fast_exp2(fast_rcp(fmaf(fabsf(qq.y - ki), LN2, EPS_LN2)) - tmax);
            float e2 = fast_exp2(fast_rcp(fmaf(fabsf(qq.z - ki), LN2, EPS_LN2)) - tmax);
            float e3 = fast_exp2(fast_rcp(fmaf(fabsf(qq.w - ki), LN2, EPS_LN2)) - tmax);
            l0 += e0; a0 = fmaf(e0, vv.x, a0);
            l1 += e1; a1 = fmaf(e1, vv.y, a1);
            l2 += e2; a2 = fmaf(e2, vv.z, a2);
            l3 += e3; a3 = fmaf(e3, vv.w, a3);
        }
        const float l = (l0 + l1) + (l2 + l3);
        const float a = (a0 + a1) + (a2 + a3);
        total += a * fast_rcp(l) * INV_SQRT_D;
    }
    out[b * D + t] = xv + total;
}

extern "C" void kernel_launch(void* const* d_in, const int* in_sizes, int n_in,
                              void* d_out, int out_size, void* d_ws, size_t ws_size,
                              hipStream_t stream) {
    const float* x  = (const float*)d_in[0];
    const float* Wq = (const float*)d_in[1];
    const float* bq = (const float*)d_in[2];
    const float* Wk = (const float*)d_in[3];
    const float* bk = (const float*)d_in[4];
    const float* Wv = (const float*)d_in[5];
    const float* bv = (const float*)d_in[6];
    float* out = (float*)d_out;

    const size_t need = (size_t)H * B * D * sizeof(float);   // 1 MB

    if (ws_size >= need) {
        float* ws = (float*)d_ws;
        attn_half<<<H * B, 1024, 0, stream>>>(x, Wq, bq, Wk, bk, Wv, bv, ws);
        reduce_h<<<(B * D) / 256, 256, 0, stream>>>(x, ws, out);
    } else {
        attn_fused<<<B, 512, 0, stream>>>(x, Wq, bq, Wk, bk, Wv, bv, out);
    }
}

// Round 13
// 36.513 us; speedup vs baseline: 1.5948x; 1.0628x over previous
//
#include <hip/hip_runtime.h>
#include <math.h>

#define H 8
#define B 64
#define D 512
#define EPS 1e-8f
#define INV_SQRT_D 0.04419417382415922f   // 1/sqrt(512)
#define LN2 0.6931471805599453f
#define EPS_LN2 6.931471805599453e-9f     // EPS * ln(2)
#define SCH_A 8388608.0f                  // 2^23
#define SCH_B 1064986823.0f               // (127 - 0.0436774)*2^23: max rel err ~3%

__device__ __forceinline__ float fast_rcp(float x) { return __builtin_amdgcn_rcpf(x); }
__device__ __forceinline__ float fast_exp2(float x) { return __builtin_amdgcn_exp2f(x); }

// Schraudolph-style approximate 2^y for y <= ~0, given pre-biased row constant
// c_row = SCH_B - tmax*SCH_A. e = reinterpret((int)max(y*2^23 + c_row, 0)).
// Underflow (y < -126) clamps to denormal/zero automatically.
__device__ __forceinline__ float sch_exp2(float r, float c_row) {
    float u = fmaf(r, SCH_A, c_row);
    u = fmaxf(u, 0.0f);
    return __int_as_float((int)u);
}

// ---------------------------------------------------------------------------
// One block per (h,b), 1024 threads = (row r, j-half). Brute-force two-pass
// softmax per half, in-LDS merge. 2 blocks/CU -> 32 waves/CU.
// Pass 2 uses Schraudolph exp2 (VALU) instead of v_exp_f32 (trans pipe).
// ---------------------------------------------------------------------------
__global__ __launch_bounds__(1024, 2) void attn_half(
    const float* __restrict__ x,
    const float* __restrict__ Wq, const float* __restrict__ bq,
    const float* __restrict__ Wk, const float* __restrict__ bk,
    const float* __restrict__ Wv, const float* __restrict__ bv,
    float* __restrict__ ws_att)
{
    const int hb = blockIdx.x;          // 0..H*B-1
    const int h = hb >> 6;              // B == 64
    const int b = hb & 63;
    const int t = threadIdx.x;          // 0..1023
    const int r = t & (D - 1);          // row 0..511
    const int half = t >> 9;            // j-half 0/1

    __shared__ __align__(16) float qs[D];
    __shared__ __align__(16) float vs[D];
    __shared__ float pT[D], pL[D], pA[D];   // half-1 partials

    const float xv = x[b * D + r];
    const float k = fmaf(Wk[h * D + r], xv, bk[h * D + r]);
    if (half == 0) {
        qs[r] = fmaf(Wq[h * D + r], xv, bq[h * D + r]);
        vs[r] = fmaf(Wv[h * D + r], xv, bv[h * D + r]);
    }
    __syncthreads();

    const float4* q4 = reinterpret_cast<const float4*>(qs) + half * (D / 8);
    const float4* v4 = reinterpret_cast<const float4*>(vs) + half * (D / 8);

    // Pass 1: dmin over this half (sub + min-with-abs-modifier, 4 chains)
    float m0 = INFINITY, m1 = INFINITY, m2 = INFINITY, m3 = INFINITY;
    for (int j = 0; j < D / 8; ++j) {
        const float4 qq = q4[j];
        m0 = fminf(m0, fabsf(qq.x - k));
        m1 = fminf(m1, fabsf(qq.y - k));
        m2 = fminf(m2, fabsf(qq.z - k));
        m3 = fminf(m3, fabsf(qq.w - k));
    }
    const float dmin = fminf(fminf(m0, m1), fminf(m2, m3));
    const float tmax = fast_rcp(fmaf(dmin, LN2, EPS_LN2));
    const float c_row = SCH_B - tmax * SCH_A;   // per-row Schraudolph bias

    // Pass 2: l, a with approximate exp2 (4 independent chains)
    float l0 = 0.f, l1 = 0.f, l2 = 0.f, l3 = 0.f;
    float a0 = 0.f, a1 = 0.f, a2 = 0.f, a3 = 0.f;
    for (int j = 0; j < D / 8; ++j) {
        const float4 qq = q4[j];
        const float4 vv = v4[j];
        const float r0 = fast_rcp(fmaf(fabsf(qq.x - k), LN2, EPS_LN2));
        const float r1 = fast_rcp(fmaf(fabsf(qq.y - k), LN2, EPS_LN2));
        const float r2 = fast_rcp(fmaf(fabsf(qq.z - k), LN2, EPS_LN2));
        const float r3 = fast_rcp(fmaf(fabsf(qq.w - k), LN2, EPS_LN2));
        const float e0 = sch_exp2(r0, c_row);
        const float e1 = sch_exp2(r1, c_row);
        const float e2 = sch_exp2(r2, c_row);
        const float e3 = sch_exp2(r3, c_row);
        l0 += e0; a0 = fmaf(e0, vv.x, a0);
        l1 += e1; a1 = fmaf(e1, vv.y, a1);
        l2 += e2; a2 = fmaf(e2, vv.z, a2);
        l3 += e3; a3 = fmaf(e3, vv.w, a3);
    }
    const float l = (l0 + l1) + (l2 + l3);
    const float a = (a0 + a1) + (a2 + a3);

    // Publish half-1 partials, merge in half-0 threads (exact exp2: 1 per row)
    if (half == 1) { pT[r] = tmax; pL[r] = l; pA[r] = a; }
    __syncthreads();
    if (half == 0) {
        const float T1 = pT[r], L1 = pL[r], A1 = pA[r];
        const float m  = fmaxf(tmax, T1);
        const float s0 = fast_exp2(tmax - m);
        const float s1 = fast_exp2(T1 - m);
        const float L  = fmaf(L1, s1, l * s0);
        const float A  = fmaf(A1, s1, a * s0);
        ws_att[hb * D + r] = A * fast_rcp(L) * INV_SQRT_D;
    }
}

// out[b,i] = x[b,i] + sum_h att[h,b,i]  (deterministic h-sum)
__global__ __launch_bounds__(256) void reduce_h(
    const float* __restrict__ x, const float* __restrict__ att,
    float* __restrict__ out)
{
    const int i = blockIdx.x * 256 + threadIdx.x;   // 0..B*D-1
    float s = x[i];
    #pragma unroll
    for (int h = 0; h < H; ++h) s += att[h * (B * D) + i];
    out[i] = s;
}

// ---------------------------------------------------------------------------
// Fallback (ws too small): fully fused exact kernel.
// ---------------------------------------------------------------------------
__global__ __launch_bounds__(512) void attn_fused(
    const float* __restrict__ x,
    const float* __restrict__ Wq, const float* __restrict__ bq,
    const float* __restrict__ Wk, const float* __restrict__ bk,
    const float* __restrict__ Wv, const float* __restrict__ bv,
    float* __restrict__ out)
{
    const int b = blockIdx.x;
    const int t = threadIdx.x;

    __shared__ float qs[D];
    __shared__ float vs[D];

    const float xv = x[b * D + t];
    float total = 0.f;

    for (int h = 0; h < H; ++h) {
        __syncthreads();
        qs[t] = Wq[h * D + t] * xv + bq[h * D + t];
        vs[t] = Wv[h * D + t] * xv + bv[h * D + t];
        const float ki = Wk[h * D + t] * xv + bk[h * D + t];
        __syncthreads();

        const float4* q4 = reinterpret_cast<const float4*>(qs);
        const float4* v4 = reinterpret_cast<const float4*>(vs);

        float d0 = INFINITY, d1 = INFINITY, d2 = INFINITY, d3 = INFINITY;
        for (int j = 0; j < D / 4; ++j) {
            float4 qq = q4[j];
            d0 = fminf(d0, fabsf(qq.x - ki));
            d1 = fminf(d1, fabsf(qq.y - ki));
            d2 = fminf(d2, fabsf(qq.z - ki));
            d3 = fminf(d3, fabsf(qq.w - ki));
        }
        const float dmin = fminf(fminf(d0, d1), fminf(d2, d3));
        const float tmax = fast_rcp(fmaf(dmin, LN2, EPS_LN2));

        float l0 = 0.f, l1 = 0.f, l2 = 0.f, l3 = 0.f;
        float a0 = 0.f, a1 = 0.f, a2 = 0.f, a3 = 0.f;
        for (int j = 0; j < D / 4; ++j) {
            float4 qq = q4[j];
            float4 vv = v4[j];
            float e0 = fast_exp2(fast_rcp(fmaf(fabsf(qq.x - ki), LN2, EPS_LN2)) - tmax);
            float e1 = fast_exp2(fast_rcp(fmaf(fabsf(qq.y - ki), LN2, EPS_LN2)) - tmax);
            float e2 = fast_exp2(fast_rcp(fmaf(fabsf(qq.z - ki), LN2, EPS_LN2)) - tmax);
            float e3 = fast_exp2(fast_rcp(fmaf(fabsf(qq.w - ki), LN2, EPS_LN2)) - tmax);
            l0 += e0; a0 = fmaf(e0, vv.x, a0);
            l1 += e1; a1 = fmaf(e1, vv.y, a1);
            l2 += e2; a2 = fmaf(e2, vv.z, a2);
            l3 += e3; a3 = fmaf(e3, vv.w, a3);
        }
        const float l = (l0 + l1) + (l2 + l3);
        const float a = (a0 + a1) + (a2 + a3);
        total += a * fast_rcp(l) * INV_SQRT_D;
    }
    out[b * D + t] = xv + total;
}

extern "C" void kernel_launch(void* const* d_in, const int* in_sizes, int n_in,
                              void* d_out, int out_size, void* d_ws, size_t ws_size,
                              hipStream_t stream) {
    const float* x  = (const float*)d_in[0];
    const float* Wq = (const float*)d_in[1];
    const float* bq = (const float*)d_in[2];
    const float* Wk = (const float*)d_in[3];
    const float* bk = (const float*)d_in[4];
    const float* Wv = (const float*)d_in[5];
    const float* bv = (const float*)d_in[6];
    float* out = (float*)d_out;

    const size_t need = (size_t)H * B * D * sizeof(float);   // 1 MB

    if (ws_size >= need) {
        float* ws = (float*)d_ws;
        attn_half<<<H * B, 1024, 0, stream>>>(x, Wq, bq, Wk, bk, Wv, bv, ws);
        reduce_h<<<(B * D) / 256, 256, 0, stream>>>(x, ws, out);
    } else {
        attn_fused<<<B, 512, 0, stream>>>(x, Wq, bq, Wk, bk, Wv, bv, out);
    }
}

// Round 14
// 35.138 us; speedup vs baseline: 1.6572x; 1.0391x over previous
//
#include <hip/hip_runtime.h>
#include <math.h>

#define H 8
#define B 64
#define D 512
#define NB 256                            // value buckets
#define EPS 1e-8f
#define INV_SQRT_D 0.04419417382415922f   // 1/sqrt(512)
#define LN2 0.6931471805599453f
#define EPS_LN2 6.931471805599453e-9f     // EPS * ln(2)
#define CUTOFF 34.0f                      // drop weights below 2^-34
#define TMAX_FALLBACK 36.0f               // flat softmax -> full range (exact)
#define SCH_A 8388608.0f                  // 2^23
#define SCH_B 1064986823.0f               // Schraudolph bias, max rel err ~3%

__device__ __forceinline__ float fast_rcp(float x) { return __builtin_amdgcn_rcpf(x); }
__device__ __forceinline__ float fast_exp2(float x) { return __builtin_amdgcn_exp2f(x); }

__device__ __forceinline__ int bucketof(float xx, float vmin, float inv_w) {
    float f = (xx - vmin) * inv_w;
    f = fminf(f, (float)(NB - 1));
    int bb = (int)f;
    return bb < 0 ? 0 : bb;
}

// Approx 2^(r - tmax) with pre-biased row constant c_row = SCH_B - tmax*2^23.
// Clamp keeps far terms at +0.0 (they are provably < 2^-34 of the sum).
__device__ __forceinline__ float sch_exp2(float r, float c_row) {
    float u = fmaf(r, SCH_A, c_row);
    u = fmaxf(u, 0.0f);
    return __int_as_float((int)u);
}

// ---------------------------------------------------------------------------
// One block per (h,b), 512 threads.
//  1. q,k,v for own column; block min/max (q,k combined) -> bucket scale
//  2. counting-sort (q,v) by q -> sq,sv; counting-sort (k,rowid) -> sk,srid
//     (two hists in parallel, two wave-parallel prefix scans, atomic scatter)
//  3. lane t takes t-th smallest k -> wave spans 64 CONSECUTIVE k's
//  4. pass 1: exact full-scan dmin over sorted q (sub+min, 4 chains)
//  5. window buckets per lane, shfl-reduced to WAVE-UNIFORM union range;
//     flat-softmax lanes force full range (exact fallback, no divergence)
//  6. pass 2: uniform float4 loop over union; all terms computed fully
//  7. scatter result to ws_att[hb*D + rid]
// ---------------------------------------------------------------------------
__global__ __launch_bounds__(512, 2) void attn_window(
    const float* __restrict__ x,
    const float* __restrict__ Wq, const float* __restrict__ bq,
    const float* __restrict__ Wk, const float* __restrict__ bk,
    const float* __restrict__ Wv, const float* __restrict__ bv,
    float* __restrict__ ws_att)
{
    const int hb = blockIdx.x;          // 0..H*B-1
    const int h = hb >> 6;              // B == 64
    const int b = hb & 63;
    const int t = threadIdx.x;
    const int wv = t >> 6, ln = t & 63;

    __shared__ __align__(16) float sq[D];
    __shared__ __align__(16) float sv[D];
    __shared__ __align__(16) float sk[D];
    __shared__ int srid[D];
    __shared__ int pfq[NB + 1], cq[NB];
    __shared__ int pfk[NB + 1], ck[NB];
    __shared__ float redlo[8], redhi[8];

    const float xv = x[b * D + t];
    const float q = fmaf(Wq[h * D + t], xv, bq[h * D + t]);
    const float v = fmaf(Wv[h * D + t], xv, bv[h * D + t]);
    const float k = fmaf(Wk[h * D + t], xv, bk[h * D + t]);

    // --- combined min/max of {q,k} ---
    float wlo = fminf(q, k), whi = fmaxf(q, k);
    #pragma unroll
    for (int off = 1; off < 64; off <<= 1) {
        wlo = fminf(wlo, __shfl_xor(wlo, off, 64));
        whi = fmaxf(whi, __shfl_xor(whi, off, 64));
    }
    if (ln == 0) { redlo[wv] = wlo; redhi[wv] = whi; }
    if (t < NB) { cq[t] = 0; ck[t] = 0; }
    __syncthreads();
    float vmin = redlo[0], vmax = redhi[0];
    #pragma unroll
    for (int i = 1; i < 8; ++i) {
        vmin = fminf(vmin, redlo[i]);
        vmax = fmaxf(vmax, redhi[i]);
    }
    const float range = vmax - vmin;
    const float inv_w = (range > 1e-30f) ? ((float)NB / range) : 0.f;

    // --- histograms ---
    const int qb = bucketof(q, vmin, inv_w);
    const int kb = bucketof(k, vmin, inv_w);
    atomicAdd(&cq[qb], 1);
    atomicAdd(&ck[kb], 1);
    __syncthreads();

    // --- two exclusive prefix scans (wave 0: q-table, wave 1: k-table) ---
    if (wv == 0) {
        const int c0 = cq[4 * ln], c1 = cq[4 * ln + 1];
        const int c2 = cq[4 * ln + 2], c3 = cq[4 * ln + 3];
        const int s = c0 + c1 + c2 + c3;
        int sc = s;
        #pragma unroll
        for (int off = 1; off < 64; off <<= 1) {
            const int n = __shfl_up(sc, off, 64);
            if (ln >= off) sc += n;
        }
        const int ex = sc - s;
        pfq[4 * ln] = ex; pfq[4 * ln + 1] = ex + c0;
        pfq[4 * ln + 2] = ex + c0 + c1; pfq[4 * ln + 3] = ex + c0 + c1 + c2;
        if (ln == 63) pfq[NB] = sc;
        cq[4 * ln] = 0; cq[4 * ln + 1] = 0; cq[4 * ln + 2] = 0; cq[4 * ln + 3] = 0;
    } else if (wv == 1) {
        const int c0 = ck[4 * ln], c1 = ck[4 * ln + 1];
        const int c2 = ck[4 * ln + 2], c3 = ck[4 * ln + 3];
        const int s = c0 + c1 + c2 + c3;
        int sc = s;
        #pragma unroll
        for (int off = 1; off < 64; off <<= 1) {
            const int n = __shfl_up(sc, off, 64);
            if (ln >= off) sc += n;
        }
        const int ex = sc - s;
        pfk[4 * ln] = ex; pfk[4 * ln + 1] = ex + c0;
        pfk[4 * ln + 2] = ex + c0 + c1; pfk[4 * ln + 3] = ex + c0 + c1 + c2;
        if (ln == 63) pfk[NB] = sc;
        ck[4 * ln] = 0; ck[4 * ln + 1] = 0; ck[4 * ln + 2] = 0; ck[4 * ln + 3] = 0;
    }
    __syncthreads();

    // --- scatter both sorts ---
    const int posq = pfq[qb] + atomicAdd(&cq[qb], 1);
    sq[posq] = q; sv[posq] = v;
    const int posk = pfk[kb] + atomicAdd(&ck[kb], 1);
    sk[posk] = k; srid[posk] = t;
    __syncthreads();

    // --- lane owns t-th smallest k ---
    const float ki = sk[t];
    const int rid = srid[t];

    // --- pass 1: exact dmin over all sorted q ---
    const float4* q4 = reinterpret_cast<const float4*>(sq);
    const float4* v4 = reinterpret_cast<const float4*>(sv);
    float m0 = INFINITY, m1 = INFINITY, m2 = INFINITY, m3 = INFINITY;
    for (int j = 0; j < D / 4; ++j) {
        const float4 qq = q4[j];
        m0 = fminf(m0, fabsf(qq.x - ki));
        m1 = fminf(m1, fabsf(qq.y - ki));
        m2 = fminf(m2, fabsf(qq.z - ki));
        m3 = fminf(m3, fabsf(qq.w - ki));
    }
    const float dmin = fminf(fminf(m0, m1), fminf(m2, m3));
    const float tmax = fast_rcp(fmaf(dmin, LN2, EPS_LN2));
    const float c_row = SCH_B - tmax * SCH_A;

    // --- per-lane window buckets; wave union (uniform bounds) ---
    int blo, bhi;
    if (tmax < TMAX_FALLBACK) {
        blo = 0; bhi = NB - 1;              // flat row: full range (exact)
    } else {
        const float rad = fast_rcp((tmax - CUTOFF) * LN2) * 1.001f;
        blo = bucketof(ki - rad, vmin, inv_w);
        bhi = bucketof(ki + rad, vmin, inv_w);
    }
    #pragma unroll
    for (int off = 1; off < 64; off <<= 1) {
        blo = min(blo, __shfl_xor(blo, off, 64));
        bhi = max(bhi, __shfl_xor(bhi, off, 64));
    }
    const int lo4 = pfq[blo] >> 2;                 // round down to float4
    const int hi4 = (pfq[bhi + 1] + 3) >> 2;       // round up (<= 128)

    // --- pass 2: uniform loop over union window ---
    float l0 = 0.f, l1 = 0.f, l2 = 0.f, l3 = 0.f;
    float a0 = 0.f, a1 = 0.f, a2 = 0.f, a3 = 0.f;
    for (int j = lo4; j < hi4; ++j) {
        const float4 qq = q4[j];
        const float4 vv = v4[j];
        const float r0 = fast_rcp(fmaf(fabsf(qq.x - ki), LN2, EPS_LN2));
        const float r1 = fast_rcp(fmaf(fabsf(qq.y - ki), LN2, EPS_LN2));
        const float r2 = fast_rcp(fmaf(fabsf(qq.z - ki), LN2, EPS_LN2));
        const float r3 = fast_rcp(fmaf(fabsf(qq.w - ki), LN2, EPS_LN2));
        const float e0 = sch_exp2(r0, c_row);
        const float e1 = sch_exp2(r1, c_row);
        const float e2 = sch_exp2(r2, c_row);
        const float e3 = sch_exp2(r3, c_row);
        l0 += e0; a0 = fmaf(e0, vv.x, a0);
        l1 += e1; a1 = fmaf(e1, vv.y, a1);
        l2 += e2; a2 = fmaf(e2, vv.z, a2);
        l3 += e3; a3 = fmaf(e3, vv.w, a3);
    }
    const float l = (l0 + l1) + (l2 + l3);
    const float a = (a0 + a1) + (a2 + a3);

    ws_att[hb * D + rid] = a * fast_rcp(l) * INV_SQRT_D;
}

// out[b,i] = x[b,i] + sum_h att[h,b,i]  (deterministic h-sum)
__global__ __launch_bounds__(256) void reduce_h(
    const float* __restrict__ x, const float* __restrict__ att,
    float* __restrict__ out)
{
    const int i = blockIdx.x * 256 + threadIdx.x;   // 0..B*D-1
    float s = x[i];
    #pragma unroll
    for (int h = 0; h < H; ++h) s += att[h * (B * D) + i];
    out[i] = s;
}

// ---------------------------------------------------------------------------
// Fallback (ws too small): fully fused exact kernel.
// ---------------------------------------------------------------------------
__global__ __launch_bounds__(512) void attn_fused(
    const float* __restrict__ x,
    const float* __restrict__ Wq, const float* __restrict__ bq,
    const float* __restrict__ Wk, const float* __restrict__ bk,
    const float* __restrict__ Wv, const float* __restrict__ bv,
    float* __restrict__ out)
{
    const int b = blockIdx.x;
    const int t = threadIdx.x;

    __shared__ float qs[D];
    __shared__ float vs[D];

    const float xv = x[b * D + t];
    float total = 0.f;

    for (int h = 0; h < H; ++h) {
        __syncthreads();
        qs[t] = Wq[h * D + t] * xv + bq[h * D + t];
        vs[t] = Wv[h * D + t] * xv + bv[h * D + t];
        const float ki = Wk[h * D + t] * xv + bk[h * D + t];
        __syncthreads();

        const float4* q4 = reinterpret_cast<const float4*>(qs);
        const float4* v4 = reinterpret_cast<const float4*>(vs);

        float d0 = INFINITY, d1 = INFINITY, d2 = INFINITY, d3 = INFINITY;
        for (int j = 0; j < D / 4; ++j) {
            float4 qq = q4[j];
            d0 = fminf(d0, fabsf(qq.x - ki));
            d1 = fminf(d1, fabsf(qq.y - ki));
            d2 = fminf(d2, fabsf(qq.z - ki));
            d3 = fminf(d3, fabsf(qq.w - ki));
        }
        const float dmin = fminf(fminf(d0, d1), fminf(d2, d3));
        const float tmax = fast_rcp(fmaf(dmin, LN2, EPS_LN2));

        float l0 = 0.f, l1 = 0.f, l2 = 0.f, l3 = 0.f;
        float a0 = 0.f, a1 = 0.f, a2 = 0.f, a3 = 0.f;
        for (int j = 0; j < D / 4; ++j) {
            float4 qq = q4[j];
            float4 vv = v4[j];
            float e0 = fast_exp2(fast_rcp(fmaf(fabsf(qq.x - ki), LN2, EPS_LN2)) - tmax);
            float e1 = fast_exp2(fast_rcp(fmaf(fabsf(qq.y - ki), LN2, EPS_LN2)) - tmax);
            float e2 = fast_exp2(fast_rcp(fmaf(fabsf(qq.z - ki), LN2, EPS_LN2)) - tmax);
            float e3 = fast_exp2(fast_rcp(fmaf(fabsf(qq.w - ki), LN2, EPS_LN2)) - tmax);
            l0 += e0; a0 = fmaf(e0, vv.x, a0);
            l1 += e1; a1 = fmaf(e1, vv.y, a1);
            l2 += e2; a2 = fmaf(e2, vv.z, a2);
            l3 += e3; a3 = fmaf(e3, vv.w, a3);
        }
        const float l = (l0 + l1) + (l2 + l3);
        const float a = (a0 + a1) + (a2 + a3);
        total += a * fast_rcp(l) * INV_SQRT_D;
    }
    out[b * D + t] = xv + total;
}

extern "C" void kernel_launch(void* const* d_in, const int* in_sizes, int n_in,
                              void* d_out, int out_size, void* d_ws, size_t ws_size,
                              hipStream_t stream) {
    const float* x  = (const float*)d_in[0];
    const float* Wq = (const float*)d_in[1];
    const float* bq = (const float*)d_in[2];
    const float* Wk = (const float*)d_in[3];
    const float* bk = (const float*)d_in[4];
    const float* Wv = (const float*)d_in[5];
    const float* bv = (const float*)d_in[6];
    float* out = (float*)d_out;

    const size_t need = (size_t)H * B * D * sizeof(float);   // 1 MB

    if (ws_size >= need) {
        float* ws = (float*)d_ws;
        attn_window<<<H * B, 512, 0, stream>>>(x, Wq, bq, Wk, bk, Wv, bv, ws);
        reduce_h<<<(B * D) / 256, 256, 0, stream>>>(x, ws, out);
    } else {
        attn_fused<<<B, 512, 0, stream>>>(x, Wq, bq, Wk, bk, Wv, bv, out);
    }
}

// Round 15
// 31.840 us; speedup vs baseline: 1.8289x; 1.1036x over previous
//
#include <hip/hip_runtime.h>
#include <math.h>

#define H 8
#define B 64
#define D 512
#define EPS 1e-8f
#define INV_SQRT_D 0.04419417382415922f   // 1/sqrt(512)
#define LN2 0.6931471805599453f
#define EPS_LN2 6.931471805599453e-9f     // EPS * ln(2)
#define SCH_A 8388608.0f                  // 2^23
#define SCH_B 1064986823.0f               // (127 - 0.0436774)*2^23, rel err ~3%

__device__ __forceinline__ float fast_rcp(float x) { return __builtin_amdgcn_rcpf(x); }
__device__ __forceinline__ float fast_exp2(float x) { return __builtin_amdgcn_exp2f(x); }

// Approx 2^(r - tmax), c_row = SCH_B - tmax*2^23.
// (unsigned) cast -> v_cvt_u32_f32 saturates negatives to 0 (far terms -> +0.0).
// r <= tmax always (rcp is monotone), so u <= SCH_B: no overflow.
__device__ __forceinline__ float sch_exp2(float r, float c_row) {
    const float u = fmaf(r, SCH_A, c_row);
    return __uint_as_float((unsigned)u);
}

// ---------------------------------------------------------------------------
// Single fused kernel. Block = (b, 64-row chunk); 1024 threads =
// (half, h, r): r = t&63 row-in-chunk, h = (t>>6)&7, half = t>>9 j-half.
//  1. stage q,v for ALL 8 heads into LDS (perfect float4 stage: thread t
//     computes flat elements 4t..4t+3 of [H][D])
//  2. per thread: two-pass Schraudolph softmax over its 256-j half
//  3. in-LDS half-merge (exact exp2 rescale), in-LDS h-reduce
//  4. out[b,i] = x[b,i] + sum_h att  (single kernel, no ws, no 2nd launch)
// ---------------------------------------------------------------------------
__global__ __launch_bounds__(1024, 2) void attn_all(
    const float* __restrict__ x,
    const float* __restrict__ Wq, const float* __restrict__ bq,
    const float* __restrict__ Wk, const float* __restrict__ bk,
    const float* __restrict__ Wv, const float* __restrict__ bv,
    float* __restrict__ out)
{
    const int blk = blockIdx.x;         // b*8 + chunk
    const int b = blk >> 3;
    const int chunk = blk & 7;
    const int t = threadIdx.x;          // 0..1023
    const int r6 = t & 63;              // row in chunk
    const int h = (t >> 6) & 7;         // head
    const int half = t >> 9;            // j-half
    const int i = chunk * 64 + r6;      // global row 0..511

    __shared__ __align__(16) float qs[H * D];   // 16 KB
    __shared__ __align__(16) float vs[H * D];   // 16 KB
    __shared__ float mT[H * 64], mL[H * 64], mA[H * 64];  // 6 KB

    // --- stage q,v for all heads: thread t owns flat elements 4t..4t+3 ---
    {
        const float4 wq = reinterpret_cast<const float4*>(Wq)[t];
        const float4 bqv = reinterpret_cast<const float4*>(bq)[t];
        const float4 wv = reinterpret_cast<const float4*>(Wv)[t];
        const float4 bvv = reinterpret_cast<const float4*>(bv)[t];
        const float4 xx = reinterpret_cast<const float4*>(x + b * D)[t & 127];
        float4 qq, vv;
        qq.x = fmaf(wq.x, xx.x, bqv.x);  vv.x = fmaf(wv.x, xx.x, bvv.x);
        qq.y = fmaf(wq.y, xx.y, bqv.y);  vv.y = fmaf(wv.y, xx.y, bvv.y);
        qq.z = fmaf(wq.z, xx.z, bqv.z);  vv.z = fmaf(wv.z, xx.z, bvv.z);
        qq.w = fmaf(wq.w, xx.w, bqv.w);  vv.w = fmaf(wv.w, xx.w, bvv.w);
        reinterpret_cast<float4*>(qs)[t] = qq;
        reinterpret_cast<float4*>(vs)[t] = vv;
    }
    const float xi = x[b * D + i];
    const float k = fmaf(Wk[h * D + i], xi, bk[h * D + i]);
    __syncthreads();

    const float4* q4 = reinterpret_cast<const float4*>(qs + h * D) + half * (D / 8);
    const float4* v4 = reinterpret_cast<const float4*>(vs + h * D) + half * (D / 8);

    // --- pass 1: dmin over this half (sub + min-with-abs, 4 chains) ---
    float m0 = INFINITY, m1 = INFINITY, m2 = INFINITY, m3 = INFINITY;
    for (int j = 0; j < D / 8; ++j) {
        const float4 qq = q4[j];
        m0 = fminf(m0, fabsf(qq.x - k));
        m1 = fminf(m1, fabsf(qq.y - k));
        m2 = fminf(m2, fabsf(qq.z - k));
        m3 = fminf(m3, fabsf(qq.w - k));
    }
    const float dmin = fminf(fminf(m0, m1), fminf(m2, m3));
    const float tmax = fast_rcp(fmaf(dmin, LN2, EPS_LN2));
    const float c_row = SCH_B - tmax * SCH_A;

    // --- pass 2: l, a with Schraudolph exp2 (4 independent chains) ---
    float l0 = 0.f, l1 = 0.f, l2 = 0.f, l3 = 0.f;
    float a0 = 0.f, a1 = 0.f, a2 = 0.f, a3 = 0.f;
    for (int j = 0; j < D / 8; ++j) {
        const float4 qq = q4[j];
        const float4 vv = v4[j];
        const float r0 = fast_rcp(fmaf(fabsf(qq.x - k), LN2, EPS_LN2));
        const float r1 = fast_rcp(fmaf(fabsf(qq.y - k), LN2, EPS_LN2));
        const float r2 = fast_rcp(fmaf(fabsf(qq.z - k), LN2, EPS_LN2));
        const float r3 = fast_rcp(fmaf(fabsf(qq.w - k), LN2, EPS_LN2));
        const float e0 = sch_exp2(r0, c_row);
        const float e1 = sch_exp2(r1, c_row);
        const float e2 = sch_exp2(r2, c_row);
        const float e3 = sch_exp2(r3, c_row);
        l0 += e0; a0 = fmaf(e0, vv.x, a0);
        l1 += e1; a1 = fmaf(e1, vv.y, a1);
        l2 += e2; a2 = fmaf(e2, vv.z, a2);
        l3 += e3; a3 = fmaf(e3, vv.w, a3);
    }
    const float l = (l0 + l1) + (l2 + l3);
    const float a = (a0 + a1) + (a2 + a3);

    // --- merge halves in LDS (exact exp2 rescale) ---
    if (half == 1) { mT[h * 64 + r6] = tmax; mL[h * 64 + r6] = l; mA[h * 64 + r6] = a; }
    __syncthreads();
    if (half == 0) {
        const float T1 = mT[h * 64 + r6], L1 = mL[h * 64 + r6], A1 = mA[h * 64 + r6];
        const float m  = fmaxf(tmax, T1);
        const float s0 = fast_exp2(tmax - m);
        const float s1 = fast_exp2(T1 - m);
        const float L  = fmaf(L1, s1, l * s0);
        const float A  = fmaf(A1, s1, a * s0);
        mT[h * 64 + r6] = A * fast_rcp(L) * INV_SQRT_D;   // reuse mT for att
    }
    __syncthreads();

    // --- h-reduce + residual + store (threads 0..63) ---
    if (t < 64) {
        float s = xi;                       // t<64 => h==0, r6==t => xi = x[b,i]
        #pragma unroll
        for (int hh = 0; hh < H; ++hh) s += mT[hh * 64 + t];
        out[b * D + chunk * 64 + t] = s;
    }
}

extern "C" void kernel_launch(void* const* d_in, const int* in_sizes, int n_in,
                              void* d_out, int out_size, void* d_ws, size_t ws_size,
                              hipStream_t stream) {
    const float* x  = (const float*)d_in[0];
    const float* Wq = (const float*)d_in[1];
    const float* bq = (const float*)d_in[2];
    const float* Wk = (const float*)d_in[3];
    const float* bk = (const float*)d_in[4];
    const float* Wv = (const float*)d_in[5];
    const float* bv = (const float*)d_in[6];
    float* out = (float*)d_out;

    attn_all<<<B * (D / 64), 1024, 0, stream>>>(x, Wq, bq, Wk, bk, Wv, bv, out);
}